// Round 7
// baseline (538.431 us; speedup 1.0000x reference)
//
#include <hip/hip_runtime.h>
#include <hip/hip_bf16.h>

#define NB 4096
#define LD_ 50
#define LC_ 50
#define LTOT 100
#define DIM 128
#define BIN 16
#define NO 64
#define KPAD 128
#define LP 136              // padded K-stride of PbfT in bf16 elems (272 B = 16*17)
#define LN_EPS 1e-5f

// conv_all grid split
#define DISC_VEC8  1600016    // 100001*128/8
#define DISC_BLKS  6251       // ceil(DISC_VEC8/256)
#define W_BLKS     1001       // 1001*2048/8/256 exact
#define T_BLKS     32
#define CONV_BLKS  (DISC_BLKS + W_BLKS + T_BLKS)

typedef __attribute__((ext_vector_type(8))) short bf16x8;
typedef __attribute__((ext_vector_type(4))) float f32x4;
typedef __attribute__((ext_vector_type(4))) unsigned ui32x4;

__device__ __forceinline__ unsigned f2bf(float f) {
    return (unsigned)__builtin_bit_cast(unsigned short, __float2bfloat16(f));
}
__device__ __forceinline__ float bf2f(unsigned u16) {   // low 16 bits = bf16
    return __builtin_bit_cast(float, u16 << 16);
}

// ---- single pre-kernel: disc_emb, w_emb -> bf16; T -> bf16 zero-padded ----
// nt-loads on the big fp32 sources (read-once; don't pollute L3).
__global__ __launch_bounds__(256) void conv_all(const float* __restrict__ disc,
                                                const float* __restrict__ w,
                                                const float* __restrict__ T,
                                                unsigned short* __restrict__ disc_bf,
                                                unsigned short* __restrict__ w_bf,
                                                unsigned short* __restrict__ Tbf) {
    const int bb = blockIdx.x;
    if (bb < DISC_BLKS) {
        size_t v = (size_t)bb * 256 + threadIdx.x;
        if (v < DISC_VEC8) {
            const f32x4* src = reinterpret_cast<const f32x4*>(disc + v * 8);
            f32x4 a = __builtin_nontemporal_load(src);
            f32x4 c = __builtin_nontemporal_load(src + 1);
            ui32x4 o;
            o[0] = f2bf(a[0]) | (f2bf(a[1]) << 16);
            o[1] = f2bf(a[2]) | (f2bf(a[3]) << 16);
            o[2] = f2bf(c[0]) | (f2bf(c[1]) << 16);
            o[3] = f2bf(c[2]) | (f2bf(c[3]) << 16);
            *reinterpret_cast<ui32x4*>(disc_bf + v * 8) = o;   // cached: read soon
        }
    } else if (bb < DISC_BLKS + W_BLKS) {
        size_t v = (size_t)(bb - DISC_BLKS) * 256 + threadIdx.x;
        const f32x4* src = reinterpret_cast<const f32x4*>(w + v * 8);
        f32x4 a = __builtin_nontemporal_load(src);
        f32x4 c = __builtin_nontemporal_load(src + 1);
        ui32x4 o;
        o[0] = f2bf(a[0]) | (f2bf(a[1]) << 16);
        o[1] = f2bf(a[2]) | (f2bf(a[3]) << 16);
        o[2] = f2bf(c[0]) | (f2bf(c[1]) << 16);
        o[3] = f2bf(c[2]) | (f2bf(c[3]) << 16);
        *reinterpret_cast<ui32x4*>(w_bf + v * 8) = o;
    } else {
        int t = (bb - DISC_BLKS - W_BLKS) * 256 + threadIdx.x;     // 0..8191
        int o = t >> 7, k = t & 127;
        float v = (k < LTOT) ? T[o * LTOT + k] : 0.f;
        Tbf[t] = (unsigned short)f2bf(v);
    }
}

__global__ __launch_bounds__(512, 6) void fused_embed_kernel(
    const int* __restrict__ dindex,    // [B,50]
    const int* __restrict__ dmask,     // [B,50]
    const float* __restrict__ cval,    // [B,50]
    const int* __restrict__ cindex,    // [B,50]
    const int* __restrict__ cmask,     // [B,50]
    const unsigned short* __restrict__ disc_bf, // [100001,128] bf16
    const float* __restrict__ v_emb,   // [1001,16]
    const float* __restrict__ b1_emb,  // [1001,16]
    const unsigned short* __restrict__ w_bf, // [1001,2048] bf16
    const float* __restrict__ b2_emb,  // [1001,128]
    const float* __restrict__ ln_gamma,// [16]
    const float* __restrict__ ln_beta, // [16]
    const float* __restrict__ T,       // [64,100] fp32 (mask path)
    const unsigned short* __restrict__ Tbf, // [64][128] bf16
    float* __restrict__ out,           // [B,64,128]
    float* __restrict__ outmask)       // [B,64] as float
{
    __shared__ unsigned short PbfT[DIM * LP];   // 34816 B, parts transposed [d][l]
    __shared__ float buf32[8][2][DIM];          // 8192 B, per-wave bounce
    __shared__ float mvec[LTOT];                // 400 B

    const int b    = blockIdx.x;
    const int tid  = threadIdx.x;
    const int wave = tid >> 6;        // 0..7
    const int lane = tid & 63;
    const int d    = tid & 127;
    const int hh   = tid >> 7;        // 0..3

    // ---- mask vector ----
    if (tid < LTOT) {
        int m = (tid < LD_) ? dmask[b * LD_ + tid] : cmask[b * LC_ + (tid - LD_)];
        mvec[tid] = 1.0f - (float)m;
    }

    // ---- zero-fill K-pad rows l=100..127 ----
    {
        unsigned short* row = &PbfT[d * LP];
        if (hh < 3) {
            *reinterpret_cast<uint2*>(&row[100 + hh * 8])     = make_uint2(0u, 0u);
            *reinterpret_cast<uint2*>(&row[100 + hh * 8 + 4]) = make_uint2(0u, 0u);
        } else {
            *reinterpret_cast<uint2*>(&row[124]) = make_uint2(0u, 0u);
        }
    }

    // ============ ISSUE PHASE: every global load before any consumer ============
    // -- 1a index loads (round trip 1, part A) --
    int idxs[12];
    #pragma unroll
    for (int i = 0; i < 3; ++i) {
        const int l0 = (hh + 4 * i) * 4;
        #pragma unroll
        for (int j = 0; j < 4; ++j)
            idxs[i * 4 + j] = dindex[b * LD_ + l0 + j];
    }
    int it0 = 0, it1 = 0;
    if (hh == 0) { it0 = dindex[b * LD_ + 48]; it1 = dindex[b * LD_ + 49]; }

    // -- 1b index/value loads (round trip 1, part B) --
    const int th    = lane >> 5;
    const int q     = lane & 31;
    const int bcast = lane & 32;
    const int npair = (wave == 0) ? 4 : 3;   // wave0: p=0,8,16,24; others 3 pairs

    int   ci[4]; float cv[4];
    #pragma unroll
    for (int j = 0; j < 4; ++j) {
        if (j < npair) {
            const int p = wave + 8 * j;
            const int t = p * 2 + th;
            ci[j] = cindex[b * LC_ + t];
            cv[j] = cval[b * LC_ + t];
        }
    }

    // -- 1a row gathers (round trip 2, part A) --
    unsigned short u[12];
    #pragma unroll
    for (int i = 0; i < 12; ++i)
        u[i] = disc_bf[(size_t)idxs[i] * DIM + d];
    unsigned short ut0 = 0, ut1 = 0;
    if (hh == 0) {
        ut0 = disc_bf[(size_t)it0 * DIM + d];
        ut1 = disc_bf[(size_t)it1 * DIM + d];
    }

    // -- 1b table gathers (round trip 2, part B): all iterations' rows in flight --
    float ve[4], b1e[4];
    float4 b2r[4];
    uint2  wr[4][16];
    #pragma unroll
    for (int j = 0; j < 4; ++j) {
        if (j < npair) {
            const int c = ci[j];
            if (q < 16) {
                ve[j]  = v_emb[c * BIN + q];
                b1e[j] = b1_emb[c * BIN + q];
            }
            b2r[j] = *reinterpret_cast<const float4*>(b2_emb + (size_t)c * DIM + q * 4);
            const uint2* wp = reinterpret_cast<const uint2*>(w_bf + (size_t)c * (BIN * DIM) + q * 4);
            #pragma unroll
            for (int k = 0; k < BIN; ++k) wr[j][k] = wp[k * 32];
        }
    }

    // ============ CONSUME PHASE ============
    // -- 1a transposed LDS stores --
    #pragma unroll
    for (int i = 0; i < 3; ++i) {
        const int l0 = (hh + 4 * i) * 4;
        unsigned lo = (unsigned)u[i*4+0] | ((unsigned)u[i*4+1] << 16);
        unsigned hi = (unsigned)u[i*4+2] | ((unsigned)u[i*4+3] << 16);
        *reinterpret_cast<uint2*>(&PbfT[d * LP + l0]) = make_uint2(lo, hi);
    }
    if (hh == 0) {
        *reinterpret_cast<unsigned int*>(&PbfT[d * LP + 48]) =
            (unsigned)ut0 | ((unsigned)ut1 << 16);
    }

    // -- 1b compute: LN + matvec + bounce-transpose --
    #pragma unroll
    for (int j = 0; j < 4; ++j) {
        if (j >= npair) break;
        const int p = wave + 8 * j;

        float a_val = 0.f;
        if (q < 16) {
            float h = cv[j] * ve[j] + b1e[j];
            float s = h;
            s += __shfl_xor(s, 1, 16);
            s += __shfl_xor(s, 2, 16);
            s += __shfl_xor(s, 4, 16);
            s += __shfl_xor(s, 8, 16);
            float mu = s * (1.f / BIN);
            float e  = h - mu;
            float v2 = e * e;
            v2 += __shfl_xor(v2, 1, 16);
            v2 += __shfl_xor(v2, 2, 16);
            v2 += __shfl_xor(v2, 4, 16);
            v2 += __shfl_xor(v2, 8, 16);
            float rstd = rsqrtf(v2 * (1.f / BIN) + LN_EPS);
            a_val = fmaxf(e * rstd * ln_gamma[q] + ln_beta[q], 0.f);
        }

        float4 acc = b2r[j];
        #pragma unroll
        for (int k = 0; k < BIN; ++k) {
            float ak = __shfl(a_val, bcast + k);
            uint2 wv = wr[j][k];
            acc.x += ak * bf2f(wv.x & 0xffffu);
            acc.y += ak * bf2f(wv.x >> 16);
            acc.z += ak * bf2f(wv.y & 0xffffu);
            acc.w += ak * bf2f(wv.y >> 16);
        }

        *reinterpret_cast<float4*>(&buf32[wave][th][q * 4]) = acc;
        __builtin_amdgcn_wave_barrier();
        float x0 = buf32[wave][0][lane];
        float x1 = buf32[wave][1][lane];
        float x2 = buf32[wave][0][lane + 64];
        float x3 = buf32[wave][1][lane + 64];
        __builtin_amdgcn_wave_barrier();
        const int l0 = 50 + p * 2;
        *reinterpret_cast<unsigned int*>(&PbfT[lane * LP + l0]) =
            f2bf(x0) | (f2bf(x1) << 16);
        *reinterpret_cast<unsigned int*>(&PbfT[(lane + 64) * LP + l0]) =
            f2bf(x2) | (f2bf(x3) << 16);
    }

    __syncthreads();   // ONE barrier: PbfT + mvec complete

    // ---- mask output (nt store) ----
    if (tid < NO) {
        float s = 0.f;
        for (int l = 0; l < LTOT; ++l) s += T[tid * LTOT + l] * mvec[l];
        float sg = (s > 0.f) ? 1.f : ((s < 0.f) ? -1.f : 0.f);
        __builtin_nontemporal_store(1.f - sg, &outmask[(size_t)b * NO + tid]);
    }

    // ---- phase 2: MFMA GEMM, 8 waves: (o-tile = wave>>1, n-half = wave&1) ----
    {
        const int ot  = wave >> 1;
        const int nh  = wave & 1;
        const int r16 = lane & 15;
        const int g4  = lane >> 4;

        f32x4 acc[4];
        #pragma unroll
        for (int nt = 0; nt < 4; ++nt) acc[nt] = (f32x4){0.f, 0.f, 0.f, 0.f};

        bf16x8 afr[4];
        const unsigned short* Ta = Tbf + (16 * ot + r16) * KPAD + g4 * 8;
        #pragma unroll
        for (int kc = 0; kc < 4; ++kc)
            afr[kc] = *reinterpret_cast<const bf16x8*>(Ta + kc * 32);

        #pragma unroll
        for (int nt = 0; nt < 4; ++nt) {
            const unsigned short* Bp = &PbfT[((nh * 4 + nt) * 16 + r16) * LP + g4 * 8];
            #pragma unroll
            for (int kc = 0; kc < 4; ++kc) {
                bf16x8 bfr = *reinterpret_cast<const bf16x8*>(Bp + kc * 32);
                acc[nt] = __builtin_amdgcn_mfma_f32_16x16x32_bf16(afr[kc], bfr, acc[nt], 0, 0, 0);
            }
        }

        // nt stores: out is write-once; don't evict the gather tables from L2/L3
        float* ob = out + (size_t)b * NO * DIM + (size_t)(16 * ot) * DIM + nh * 64;
        #pragma unroll
        for (int nt = 0; nt < 4; ++nt) {
            #pragma unroll
            for (int r = 0; r < 4; ++r) {
                __builtin_nontemporal_store(acc[nt][r],
                    &ob[(g4 * 4 + r) * DIM + nt * 16 + r16]);
            }
        }
    }
}

extern "C" void kernel_launch(void* const* d_in, const int* in_sizes, int n_in,
                              void* d_out, int out_size, void* d_ws, size_t ws_size,
                              hipStream_t stream) {
    const int*   dindex  = (const int*)  d_in[0];
    const int*   dmask   = (const int*)  d_in[1];
    const float* cval    = (const float*)d_in[2];
    const int*   cindex  = (const int*)  d_in[3];
    const int*   cmask   = (const int*)  d_in[4];
    const float* disc_emb= (const float*)d_in[5];
    const float* v_emb   = (const float*)d_in[6];
    const float* b1_emb  = (const float*)d_in[7];
    const float* w_emb   = (const float*)d_in[8];
    const float* b2_emb  = (const float*)d_in[9];
    const float* lng     = (const float*)d_in[10];
    const float* lnb     = (const float*)d_in[11];
    const float* T       = (const float*)d_in[12];

    float* out     = (float*)d_out;
    float* outmask = out + (size_t)NB * NO * DIM;

    // workspace: disc_bf 25,600,256 B | w_bf 4,100,096 B | Tbf 16,384 B
    unsigned short* disc_bf = (unsigned short*)d_ws;
    unsigned short* w_bf    = (unsigned short*)((char*)d_ws + 25600256);
    unsigned short* Tbf     = (unsigned short*)((char*)d_ws + 25600256 + 4100096);

    hipLaunchKernelGGL(conv_all, dim3(CONV_BLKS), dim3(256), 0, stream,
                       disc_emb, w_emb, T, disc_bf, w_bf, Tbf);
    hipLaunchKernelGGL(fused_embed_kernel, dim3(NB), dim3(512), 0, stream,
                       dindex, dmask, cval, cindex, cmask,
                       disc_bf, v_emb, b1_emb, w_bf, b2_emb,
                       lng, lnb, T, Tbf, out, outmask);
}